// Round 13
// baseline (3430.017 us; speedup 1.0000x reference)
//
#include <hip/hip_runtime.h>

#define N_NODES 100000
#define N_EDGES 3200000
#define N_IN    128
#define N_OUT   64
#define ITERS   150
#define LEAK    0.01f

#define NBLK    256            // 1 block per CU
#define NT      960            // 15 waves
#define RPB     391            // ceil(100000/256) rows per block
#define NLINE   6250           // 64B y-lines: ceil(100000/16)
#define NKEYS   (NBLK * NLINE) // 1.6M (block, line) buckets
#define SCAN_CHUNK 1024
#define SCAN_NBLK  1563        // 1563*1024 >= NKEYS+1
#define ARRSTR  16             // ints between arrival slots (64B)
#define YSTR    100096         // y buffer stride (float4-aligned)
#define NBUF    150
#define COLMASK 0x1FFFF        // 17 bits

__device__ __forceinline__ float mml(float v) {
    v = (v < 0.0f) ? v * LEAK : v;
    if (v > 0.5f) v = 1.0f - 0.25f / v;
    return v;
}

__global__ void k_binit(const float* __restrict__ biases, float* __restrict__ b_in) {
    int i = blockIdx.x * blockDim.x + threadIdx.x;
    if (i < N_NODES) b_in[i] = biases[i];
}

// node_in.at[in_indices].set(in_w * x) -> last-write-wins for duplicates
__global__ void k_scatter_in(const float* __restrict__ x,
                             const float* __restrict__ in_w,
                             const int*   __restrict__ in_idx,
                             const float* __restrict__ biases,
                             float* __restrict__ b_in) {
    int k = threadIdx.x;
    if (k < N_IN) {
        int idx = in_idx[k];
        bool last = true;
        for (int j = k + 1; j < N_IN; ++j)
            if (in_idx[j] == idx) { last = false; break; }
        if (last) b_in[idx] = biases[idx] + in_w[k] * x[k];
    }
}

// y^(1) = act(0 + b_in)
__global__ void k_y0(const float* __restrict__ b_in, float* __restrict__ y0) {
    int i = blockIdx.x * blockDim.x + threadIdx.x;
    if (i < N_NODES) y0[i] = mml(b_in[i]);
}

// histogram over (block, y-line) buckets -> per-block slabs sorted by line
__global__ void k_hist(const int* __restrict__ rows, const int* __restrict__ cols,
                       int* __restrict__ counts) {
    int i = blockIdx.x * blockDim.x + threadIdx.x;
    int stride = gridDim.x * blockDim.x;
    for (; i < N_EDGES; i += stride) {
        int key = (rows[i] / RPB) * NLINE + (cols[i] >> 4);
        atomicAdd(&counts[key], 1);
    }
}

__global__ void k_scan1(const int* __restrict__ counts, int* __restrict__ rp,
                        int* __restrict__ blockSums) {
    __shared__ int sm[SCAN_CHUNK];
    int t = threadIdx.x;
    int i = blockIdx.x * SCAN_CHUNK + t;
    int v = (i < NKEYS) ? counts[i] : 0;
    sm[t] = v;
    __syncthreads();
    for (int off = 1; off < SCAN_CHUNK; off <<= 1) {
        int add = (t >= off) ? sm[t - off] : 0;
        __syncthreads();
        sm[t] += add;
        __syncthreads();
    }
    if (i <= NKEYS) rp[i] = sm[t] - v;
    if (t == SCAN_CHUNK - 1) blockSums[blockIdx.x] = sm[t];
}

// Blelloch exclusive scan over 2048 slots (covers SCAN_NBLK=1563)
__global__ void k_scan2(int* __restrict__ blockSums) {
    __shared__ int sm[2048];
    int t = threadIdx.x;
    sm[t]        = (t < SCAN_NBLK) ? blockSums[t] : 0;
    sm[t + 1024] = (t + 1024 < SCAN_NBLK) ? blockSums[t + 1024] : 0;
    __syncthreads();
    for (int d = 1; d < 2048; d <<= 1) {
        int idx = (t + 1) * (d << 1) - 1;
        if (idx < 2048) sm[idx] += sm[idx - d];
        __syncthreads();
    }
    if (t == 0) sm[2047] = 0;
    __syncthreads();
    for (int d = 1024; d >= 1; d >>= 1) {
        int idx = (t + 1) * (d << 1) - 1;
        if (idx < 2048) { int tmp = sm[idx - d]; sm[idx - d] = sm[idx]; sm[idx] += tmp; }
        __syncthreads();
    }
    if (t < SCAN_NBLK) blockSums[t] = sm[t];
    if (t + 1024 < SCAN_NBLK) blockSums[t + 1024] = sm[t + 1024];
}

__global__ void k_scan3(int* __restrict__ rp, const int* __restrict__ blockSums,
                        int* __restrict__ next) {
    int i = blockIdx.x * SCAN_CHUNK + threadIdx.x;
    if (i <= NKEYS) {
        int val = rp[i] + blockSums[blockIdx.x];
        rp[i] = val;
        if (i < NKEYS) next[i] = val;
    }
}

// fill: packed (col | rowloc<<17, weight); slab per block, line-sorted
__global__ void k_scatter_edges(const int* __restrict__ rows, const int* __restrict__ cols,
                                const float* __restrict__ w,
                                int* __restrict__ next, int2* __restrict__ csr) {
    int i = blockIdx.x * blockDim.x + threadIdx.x;
    int stride = gridDim.x * blockDim.x;
    for (; i < N_EDGES; i += stride) {
        int r = rows[i], c = cols[i];
        int blk = r / RPB;
        int key = blk * NLINE + (c >> 4);
        int p = atomicAdd(&next[key], 1);
        csr[p] = make_int2(c | ((r - blk * RPB) << 17), __float_as_int(w[i]));
    }
}

// Per iteration: stream the block's line-sorted slab (coalesced CSR reads,
// TA-merged y gathers), ds_add_f32 into acc[RPB], then finalize + rendezvous.
template <bool SC1>
__global__ __launch_bounds__(NT) void k_iterate(
    const int*  __restrict__ rp2k,
    const int2* __restrict__ csr,
    const float* __restrict__ b_in,
    float* __restrict__ ybufs,
    int* __restrict__ arr,
    const int* __restrict__ out_idx,
    const float* __restrict__ out_w,
    float* __restrict__ out,
    int nbuf)
{
    __shared__ float acc[RPB];
    const int b = blockIdx.x, t = threadIdx.x;
    const int row0 = b * RPB;
    const int row_end = (row0 + RPB < N_NODES) ? row0 + RPB : N_NODES;
    const int nrows = row_end - row0;
    const int sbeg = rp2k[b * NLINE];
    const int send = rp2k[(b + 1) * NLINE];
    const float bi = (t < nrows) ? b_in[row0 + t] : 0.f;

    for (int i = t; i < RPB; i += NT) acc[i] = 0.f;
    __syncthreads();

    for (int it = 1; it <= ITERS - 1; ++it) {
        const float* ysrc = ybufs + (size_t)((it - 1) % nbuf) * YSTR;
        float*       ydst = ybufs + (size_t)(it % nbuf) * YSTR;

        // gather + LDS-atomic accumulate, 2-deep clamped MLP
        const int last = send - 1;
        for (int e = sbeg + t; e < send; e += 2 * NT) {
            const int eb = e + NT;
            const int2 u0 = csr[e];
            const int2 u1 = csr[(eb < last) ? eb : last];
            float y0, y1;
            if (SC1) {
                y0 = __hip_atomic_load(&ysrc[u0.x & COLMASK], __ATOMIC_RELAXED, __HIP_MEMORY_SCOPE_AGENT);
                y1 = __hip_atomic_load(&ysrc[u1.x & COLMASK], __ATOMIC_RELAXED, __HIP_MEMORY_SCOPE_AGENT);
            } else {
                y0 = ysrc[u0.x & COLMASK];
                y1 = ysrc[u1.x & COLMASK];
            }
            const float w0 = __int_as_float(u0.y);
            const float w1 = (eb < send) ? __int_as_float(u1.y) : 0.f;
            __hip_atomic_fetch_add(&acc[u0.x >> 17], w0 * y0,
                                   __ATOMIC_RELAXED, __HIP_MEMORY_SCOPE_WORKGROUP);
            __hip_atomic_fetch_add(&acc[u1.x >> 17], w1 * y1,
                                   __ATOMIC_RELAXED, __HIP_MEMORY_SCOPE_WORKGROUP);
        }
        __syncthreads();               // all ds_adds done

        if (t < nrows) {
            const float v = mml(bi + acc[t]);
            __hip_atomic_store(&ydst[row0 + t], v,
                               __ATOMIC_RELAXED, __HIP_MEMORY_SCOPE_AGENT);
            acc[t] = 0.f;              // re-zero for next iteration
        }
        asm volatile("s_waitcnt vmcnt(0)" ::: "memory");  // y stores ack'd at MALL
        __builtin_amdgcn_s_barrier();                     // all waves drained
        if (t == 0)
            __hip_atomic_store(&arr[b * ARRSTR], it, __ATOMIC_RELAXED,
                               __HIP_MEMORY_SCOPE_AGENT);
        if (t < NBLK) {
            while (__hip_atomic_load(&arr[t * ARRSTR], __ATOMIC_RELAXED,
                                     __HIP_MEMORY_SCOPE_AGENT) < it)
                __builtin_amdgcn_s_sleep(1);
        }
        __syncthreads();
    }

    if (b == 0 && t < N_OUT) {
        const float* yfin = ybufs + (size_t)((ITERS - 1) % nbuf) * YSTR;
        out[t] = out_w[t] * __hip_atomic_load(&yfin[out_idx[t]],
                   __ATOMIC_RELAXED, __HIP_MEMORY_SCOPE_AGENT);
    }
}

extern "C" void kernel_launch(void* const* d_in, const int* in_sizes, int n_in,
                              void* d_out, int out_size, void* d_ws, size_t ws_size,
                              hipStream_t stream) {
    const float* x      = (const float*)d_in[0];
    const float* in_w   = (const float*)d_in[1];
    const float* rec_w  = (const float*)d_in[2];
    const float* biases = (const float*)d_in[3];
    const float* out_w  = (const float*)d_in[4];
    const int*   in_idx = (const int*)d_in[5];
    const int*   e_rows = (const int*)d_in[6];
    const int*   e_cols = (const int*)d_in[7];
    const int*   out_idx= (const int*)d_in[8];
    float* out = (float*)d_out;

    char* ws = (char*)d_ws;
    float* b_in    = (float*)ws;                       // 100000 f
    int*   rp2k    = (int*)(b_in + N_NODES);           // NKEYS+1 (+pad)
    int*   counts  = rp2k + (NKEYS + 64);              // NKEYS (also `next`)
    int*   blockSums = counts + NKEYS;                 // 2048
    int*   arr     = blockSums + 2048;                 // NBLK*ARRSTR
    size_t off = (size_t)((char*)(arr + NBLK * ARRSTR) - ws);
    off = (off + 255) & ~(size_t)255;
    int2* csr = (int2*)(ws + off);                     // 25.6 MB
    size_t off2 = off + (size_t)N_EDGES * sizeof(int2);
    off2 = (off2 + 255) & ~(size_t)255;
    float* ybufs = (float*)(ws + off2);

    long long avail = ((long long)ws_size - (long long)off2) /
                      (long long)(YSTR * sizeof(float));
    int nbuf, sc1mode;
    if (avail >= NBUF) { nbuf = NBUF; sc1mode = 0; }   // cold-L2 invariant
    else               { nbuf = 2;    sc1mode = 1; }   // sc1 gathers

    hipMemsetAsync(counts, 0, (size_t)NKEYS * sizeof(int), stream);
    hipMemsetAsync(arr, 0, NBLK * ARRSTR * sizeof(int), stream);

    k_binit<<<391, 256, 0, stream>>>(biases, b_in);
    k_scatter_in<<<1, 128, 0, stream>>>(x, in_w, in_idx, biases, b_in);
    k_y0<<<391, 256, 0, stream>>>(b_in, ybufs);        // buffer 0 = y^(1)

    k_hist<<<1024, 256, 0, stream>>>(e_rows, e_cols, counts);
    k_scan1<<<SCAN_NBLK, SCAN_CHUNK, 0, stream>>>(counts, rp2k, blockSums);
    k_scan2<<<1, 1024, 0, stream>>>(blockSums);
    k_scan3<<<SCAN_NBLK, SCAN_CHUNK, 0, stream>>>(rp2k, blockSums, counts);
    k_scatter_edges<<<1024, 256, 0, stream>>>(e_rows, e_cols, rec_w, counts, csr);

    int*   rp_a   = rp2k;
    int2*  csr_a  = csr;
    float* bin_a  = b_in;
    float* yb_a   = ybufs;
    int*   arr_a  = arr;
    const int*   oidx_a = out_idx;
    const float* ow_a   = out_w;
    float* out_a  = out;
    void* args[] = { &rp_a, &csr_a, &bin_a, &yb_a, &arr_a,
                     &oidx_a, &ow_a, &out_a, &nbuf };
    void* kfn = sc1mode ? (void*)k_iterate<true> : (void*)k_iterate<false>;
    hipLaunchCooperativeKernel(kfn, dim3(NBLK), dim3(NT), args, 0, stream);
}